// Round 6
// baseline (394.009 us; speedup 1.0000x reference)
//
#include <hip/hip_runtime.h>
#include <hip/hip_cooperative_groups.h>

namespace cg = cooperative_groups;

#define B_SZ 8
#define L_SEQ 144
#define NTOK 1152
#define D_MODEL 256
#define D_INNER 512
#define D_STATE 64
#define DT_RANK 4
#define LP 40
#define NTHR 256

typedef __attribute__((ext_vector_type(8))) short bf16x8;   // MFMA A/B frag
typedef __attribute__((ext_vector_type(4))) float f32x4;    // MFMA C/D frag
typedef __attribute__((ext_vector_type(4))) short short4v;

__device__ __forceinline__ unsigned short bf16_rn(float f) {
    unsigned u = __float_as_uint(f);
    u += 0x7FFF + ((u >> 16) & 1);
    return (unsigned short)(u >> 16);
}
__device__ __forceinline__ float bf16_f(unsigned short h) {
    return __uint_as_float(((unsigned)h) << 16);
}
__device__ __forceinline__ unsigned packsplit(float f) {   // hi | lo<<16
    const unsigned short h = bf16_rn(f);
    const unsigned short l = bf16_rn(f - bf16_f(h));
    return (unsigned)h | ((unsigned)l << 16);
}

// ---------------------------------------------------------------------------
// One 64x64 tile of C[M,N] = A[M,K] . B[N,K]^T via bf16x3 split MFMA.
// (identical math to the R4-passing gemm_mfma)
// ---------------------------------------------------------------------------
template<bool APACK, bool GN>
__device__ __forceinline__ void gemm_tile(const void* __restrict__ Aptr,
                                          const float* __restrict__ Bptr,
                                          float* __restrict__ C,
                                          const int N, const int K,
                                          const int lda, const int ldb, const int ldc,
                                          const int m0, const int n0,
                                          short* __restrict__ Ah, short* __restrict__ Al,
                                          short* __restrict__ Bh, short* __restrict__ Bl) {
    const float* Af = (const float*)Aptr;
    const unsigned* Au = (const unsigned*)Aptr;
    const int tid = threadIdx.x;
    const int w = tid >> 6, l = tid & 63;
    const int lm = l & 15, lq = l >> 4;
    const int m0w = (w >> 1) * 32, n0w = (w & 1) * 32;
    f32x4 acc[2][2] = {};

    for (int k0 = 0; k0 < K; k0 += 32) {
        unsigned short ha[2][4], la[2][4], hb[2][4], lb[2][4];
#pragma unroll
        for (int p = 0; p < 2; ++p) {
            const int i = tid + 256 * p;
            const int r = i >> 3, c = (i & 7) * 4;
            if (APACK) {
                const uint4 v = *(const uint4*)(Au + (size_t)(m0 + r) * lda + k0 + c);
                ha[p][0] = v.x & 0xFFFF; la[p][0] = v.x >> 16;
                ha[p][1] = v.y & 0xFFFF; la[p][1] = v.y >> 16;
                ha[p][2] = v.z & 0xFFFF; la[p][2] = v.z >> 16;
                ha[p][3] = v.w & 0xFFFF; la[p][3] = v.w >> 16;
            } else {
                const float4 v = *(const float4*)(Af + (size_t)(m0 + r) * lda + k0 + c);
                ha[p][0] = bf16_rn(v.x); la[p][0] = bf16_rn(v.x - bf16_f(ha[p][0]));
                ha[p][1] = bf16_rn(v.y); la[p][1] = bf16_rn(v.y - bf16_f(ha[p][1]));
                ha[p][2] = bf16_rn(v.z); la[p][2] = bf16_rn(v.z - bf16_f(ha[p][2]));
                ha[p][3] = bf16_rn(v.w); la[p][3] = bf16_rn(v.w - bf16_f(ha[p][3]));
            }
            float4 bv = make_float4(0.f, 0.f, 0.f, 0.f);
            if (!GN || (n0 + r) < N)
                bv = *(const float4*)(Bptr + (size_t)(n0 + r) * ldb + k0 + c);
            hb[p][0] = bf16_rn(bv.x); lb[p][0] = bf16_rn(bv.x - bf16_f(hb[p][0]));
            hb[p][1] = bf16_rn(bv.y); lb[p][1] = bf16_rn(bv.y - bf16_f(hb[p][1]));
            hb[p][2] = bf16_rn(bv.z); lb[p][2] = bf16_rn(bv.z - bf16_f(hb[p][2]));
            hb[p][3] = bf16_rn(bv.w); lb[p][3] = bf16_rn(bv.w - bf16_f(hb[p][3]));
        }
        __syncthreads();
#pragma unroll
        for (int p = 0; p < 2; ++p) {
            const int i = tid + 256 * p;
            const int r = i >> 3, c = (i & 7) * 4;
            const int o = r * LP + c;
            short4v v;
            v = (short4v){(short)ha[p][0], (short)ha[p][1], (short)ha[p][2], (short)ha[p][3]};
            *(short4v*)&Ah[o] = v;
            v = (short4v){(short)la[p][0], (short)la[p][1], (short)la[p][2], (short)la[p][3]};
            *(short4v*)&Al[o] = v;
            v = (short4v){(short)hb[p][0], (short)hb[p][1], (short)hb[p][2], (short)hb[p][3]};
            *(short4v*)&Bh[o] = v;
            v = (short4v){(short)lb[p][0], (short)lb[p][1], (short)lb[p][2], (short)lb[p][3]};
            *(short4v*)&Bl[o] = v;
        }
        __syncthreads();
        bf16x8 fah[2], fal[2], fbh[2], fbl[2];
#pragma unroll
        for (int t = 0; t < 2; ++t) {
            const int ao = (m0w + t * 16 + lm) * LP + lq * 8;
            fah[t] = *(const bf16x8*)&Ah[ao];
            fal[t] = *(const bf16x8*)&Al[ao];
            const int bo = (n0w + t * 16 + lm) * LP + lq * 8;
            fbh[t] = *(const bf16x8*)&Bh[bo];
            fbl[t] = *(const bf16x8*)&Bl[bo];
        }
#pragma unroll
        for (int mt = 0; mt < 2; ++mt)
#pragma unroll
            for (int nt = 0; nt < 2; ++nt) {
                acc[mt][nt] = __builtin_amdgcn_mfma_f32_16x16x32_bf16(
                    fal[mt], fbh[nt], acc[mt][nt], 0, 0, 0);
                acc[mt][nt] = __builtin_amdgcn_mfma_f32_16x16x32_bf16(
                    fah[mt], fbl[nt], acc[mt][nt], 0, 0, 0);
                acc[mt][nt] = __builtin_amdgcn_mfma_f32_16x16x32_bf16(
                    fah[mt], fbh[nt], acc[mt][nt], 0, 0, 0);
            }
    }
    // C/D layout: col = lane&15 (n), row = (lane>>4)*4 + reg (m)
#pragma unroll
    for (int mt = 0; mt < 2; ++mt) {
        const int gm = m0 + m0w + mt * 16 + lq * 4;
#pragma unroll
        for (int nt = 0; nt < 2; ++nt) {
            const int gn = n0 + n0w + nt * 16 + lm;
            if (!GN || gn < N) {
#pragma unroll
                for (int r = 0; r < 4; ++r)
                    C[(size_t)(gm + r) * ldc + gn] = acc[mt][nt][r];
            }
        }
    }
}

// ---------------------------------------------------------------------------
// Phase bodies (grid-size-agnostic; blk/gsz passed in)
// ---------------------------------------------------------------------------
__device__ __forceinline__ void phase_gemm1(int blk, int gsz,
        const float* W_in, const float* x, float* xzT,
        short* Ah, short* Al, short* Bh, short* Bl) {
    for (int t = blk; t < 288; t += gsz) {
        const int bx = t % 18, by = t / 18;
        gemm_tile<false, false>(W_in, x, xzT, NTOK, D_MODEL, D_MODEL, D_MODEL, NTOK,
                                by * 64, bx * 64, Ah, Al, Bh, Bl);
    }
}

__device__ __forceinline__ void phase_conv(int blk, int gsz,
        const float* xzT, const float* conv_w, const float* conv_b,
        float* ixT, unsigned* ixM) {
    for (int idx = blk * NTHR + threadIdx.x; idx < D_INNER * NTOK; idx += gsz * NTHR) {
        const int d = idx / NTOK;
        const int tok = idx - d * NTOK;
        const int b = tok / L_SEQ;
        const int t = tok - b * L_SEQ;
        const float* row = xzT + (size_t)d * NTOK + tok;
        const float4 cw4 = *(const float4*)(conv_w + d * 4);
        float s = conv_b[d];
        if (t >= 2) s = fmaf(cw4.x, row[-2], s);
        if (t >= 1) s = fmaf(cw4.y, row[-1], s);
        s = fmaf(cw4.z, row[0], s);
        if (t < L_SEQ - 1) s = fmaf(cw4.w, row[1], s);
        const float r = s * __builtin_amdgcn_rcpf(1.f + __expf(-s));
        ixT[idx] = r;
        ixM[(size_t)tok * D_INNER + d] = packsplit(r);
    }
}

__device__ __forceinline__ void phase_gemm3(int blk, int gsz,
        const unsigned* ixM, const float* W_x, float* dBC,
        short* Ah, short* Al, short* Bh, short* Bl) {
    for (int t = blk; t < 54; t += gsz) {
        const int bx = t % 3, by = t / 3;
        gemm_tile<true, true>(ixM, W_x, dBC, 132, D_INNER, D_INNER, D_INNER, 132,
                              by * 64, bx * 64, Ah, Al, Bh, Bl);
    }
}

__device__ __forceinline__ void phase_scan(int blk, int gsz,
        const float* dBC, const float* xzT, const float* ixT,
        const float* W_dt, const float* b_dt, const float* A_log,
        const float* Dp, unsigned* gM, char* smem) {
    float4* aux_s = (float4*)smem;                  // [4][16] float4 = 1024 B
    float* Pb = (float*)(smem + 1024);              // [4][16*65]   = 16640 B
    const int w = threadIdx.x >> 6, lane = threadIdx.x & 63;
    float4* aux_w = aux_s + w * 16;
    float (*Pw)[65] = (float(*)[65])(Pb + w * 16 * 65);
    for (int u = blk; u < 1024; u += gsz) {         // unit = (b, group of 4 d)
        const int b = u >> 7, dg = u & 127;
        const int d = (dg << 2) | w;
        const int base = b * L_SEQ;
        const float An2 = -__expf(A_log[(d << 6) + lane]) * 1.44269504088896f;
        const float4 wdt = *(const float4*)(W_dt + (d << 2));
        const float bdt = b_dt[d], dpv = Dp[d];
        float h = 0.f;
#pragma unroll 1
        for (int c = 0; c < 9; ++c) {               // 9 x 16 = 144 tokens
            const int t0 = c * 16;
            if (lane < 16) {
                const int tok = base + t0 + lane;
                const float4 dt4 = *(const float4*)(dBC + (size_t)tok * 132);
                float s = fmaf(dt4.x, wdt.x, bdt);
                s = fmaf(dt4.y, wdt.y, s);
                s = fmaf(dt4.z, wdt.z, s);
                s = fmaf(dt4.w, wdt.w, s);
                const float delta = fmaxf(s, 0.f) + __logf(1.f + __expf(-fabsf(s)));
                const float ixv = ixT[(size_t)d * NTOK + tok];
                const float zv  = xzT[(size_t)(D_INNER + d) * NTOK + tok];
                const float sz  = zv * __builtin_amdgcn_rcpf(1.f + __expf(-zv));
                aux_w[lane] = make_float4(delta, delta * ixv, dpv * ixv, sz);
            }
#pragma unroll 8
            for (int i = 0; i < 16; ++i) {
                const size_t rb = (size_t)(base + t0 + i) * 132;
                const float Bv = dBC[rb + DT_RANK + lane];
                const float Cv = dBC[rb + DT_RANK + D_STATE + lane];
                const float4 a4 = aux_w[i];
                const float dA = __builtin_amdgcn_exp2f(a4.x * An2);
                h = fmaf(dA, h, a4.y * Bv);
                Pw[i][lane] = h * Cv;
            }
            const int tl = lane & 31, hf = lane >> 5;
            float s2 = 0.f;
            if (tl < 16) {
#pragma unroll
                for (int j = 0; j < 32; ++j) s2 += Pw[tl][hf * 32 + j];
            }
            s2 += __shfl_xor(s2, 32, 64);
            if (hf == 0 && tl < 16) {
                const float4 a4 = aux_w[tl];
                gM[(size_t)(base + t0 + tl) * D_INNER + d] =
                    packsplit((s2 + a4.z) * a4.w);
            }
        }
    }
}

__device__ __forceinline__ void phase_gemm7(int blk, int gsz,
        const unsigned* gM, const float* W_out, float* out,
        short* Ah, short* Al, short* Bh, short* Bl) {
    for (int t = blk; t < 72; t += gsz) {
        const int bx = t % 4, by = t / 4;
        gemm_tile<true, false>(gM, W_out, out, D_MODEL, D_INNER, D_INNER, D_INNER,
                               D_MODEL, by * 64, bx * 64, Ah, Al, Bh, Bl);
    }
}

// ---------------------------------------------------------------------------
// Cooperative mega-kernel (grid sized by occupancy query at launch)
// ---------------------------------------------------------------------------
__global__ __launch_bounds__(NTHR, 2) void mega_k(
        const float* __restrict__ x, const float* __restrict__ W_in,
        const float* __restrict__ conv_w, const float* __restrict__ conv_b,
        const float* __restrict__ W_x, const float* __restrict__ W_dt,
        const float* __restrict__ b_dt, const float* __restrict__ A_log,
        const float* __restrict__ Dp, const float* __restrict__ W_out,
        float* __restrict__ out,
        float* __restrict__ xzT, float* __restrict__ ixT,
        unsigned* __restrict__ ixM, float* __restrict__ dBC,
        unsigned* __restrict__ gM) {
    __shared__ __align__(16) char smem[4 * 64 * LP * 2];   // 20480 B
    short* Ah = (short*)smem;
    short* Al = Ah + 64 * LP;
    short* Bh = Al + 64 * LP;
    short* Bl = Bh + 64 * LP;
    cg::grid_group grid = cg::this_grid();
    const int blk = blockIdx.x, gsz = gridDim.x;

    phase_gemm1(blk, gsz, W_in, x, xzT, Ah, Al, Bh, Bl);
    grid.sync();
    phase_conv(blk, gsz, xzT, conv_w, conv_b, ixT, ixM);
    grid.sync();
    phase_gemm3(blk, gsz, ixM, W_x, dBC, Ah, Al, Bh, Bl);
    grid.sync();
    phase_scan(blk, gsz, dBC, xzT, ixT, W_dt, b_dt, A_log, Dp, gM, smem);
    grid.sync();
    phase_gemm7(blk, gsz, gM, W_out, out, Ah, Al, Bh, Bl);
}

// ---------------------------------------------------------------------------
// Non-cooperative fallback kernels (same phase code, separate dispatches)
// ---------------------------------------------------------------------------
#define SMEM_DECL __shared__ __align__(16) char smem[4 * 64 * LP * 2]; \
    short* Ah = (short*)smem; short* Al = Ah + 64 * LP; \
    short* Bh = Al + 64 * LP; short* Bl = Bh + 64 * LP;

__global__ __launch_bounds__(NTHR, 2) void k1(const float* W_in, const float* x,
                                              float* xzT) {
    SMEM_DECL;
    phase_gemm1(blockIdx.x, gridDim.x, W_in, x, xzT, Ah, Al, Bh, Bl);
}
__global__ __launch_bounds__(NTHR, 2) void k2(const float* xzT, const float* cw,
                                              const float* cb, float* ixT,
                                              unsigned* ixM) {
    phase_conv(blockIdx.x, gridDim.x, xzT, cw, cb, ixT, ixM);
}
__global__ __launch_bounds__(NTHR, 2) void k3(const unsigned* ixM, const float* W_x,
                                              float* dBC) {
    SMEM_DECL;
    phase_gemm3(blockIdx.x, gridDim.x, ixM, W_x, dBC, Ah, Al, Bh, Bl);
}
__global__ __launch_bounds__(NTHR, 2) void k4(const float* dBC, const float* xzT,
                                              const float* ixT, const float* W_dt,
                                              const float* b_dt, const float* A_log,
                                              const float* Dp, unsigned* gM) {
    __shared__ __align__(16) char smem[4 * 64 * LP * 2];
    phase_scan(blockIdx.x, gridDim.x, dBC, xzT, ixT, W_dt, b_dt, A_log, Dp, gM, smem);
}
__global__ __launch_bounds__(NTHR, 2) void k5(const unsigned* gM, const float* W_out,
                                              float* out) {
    SMEM_DECL;
    phase_gemm7(blockIdx.x, gridDim.x, gM, W_out, out, Ah, Al, Bh, Bl);
}

// ---------------------------------------------------------------------------
extern "C" void kernel_launch(void* const* d_in, const int* in_sizes, int n_in,
                              void* d_out, int out_size, void* d_ws, size_t ws_size,
                              hipStream_t stream) {
    const float* x      = (const float*)d_in[0];
    // d_in[1] = lastin (unused: reference starts from h0 = 0)
    const float* W_in   = (const float*)d_in[2];
    const float* conv_w = (const float*)d_in[3];
    const float* conv_b = (const float*)d_in[4];
    const float* W_x    = (const float*)d_in[5];
    const float* W_dt   = (const float*)d_in[6];
    const float* b_dt   = (const float*)d_in[7];
    const float* A_log  = (const float*)d_in[8];
    const float* Dp     = (const float*)d_in[9];
    const float* W_out  = (const float*)d_in[10];
    float* out = (float*)d_out;

    float* ws  = (float*)d_ws;
    float* xzT = ws;                            // [1024][1152] f32
    float* ixT = xzT + 1179648;                 // [512][1152]  f32
    float* dBC = ixT + 589824;                  // [1152][132]  f32
    unsigned* ixM = (unsigned*)(dBC + 152064);  // [1152][512]  packed bf16 pair
    unsigned* gM  = ixM + 589824;               // [1152][512]  packed bf16 pair

    // Host-only queries (capture-safe, deterministic)
    int dev = 0;
    (void)hipGetDevice(&dev);
    int coop = 0;
    (void)hipDeviceGetAttribute(&coop, hipDeviceAttributeCooperativeLaunch, dev);
    int maxBlk = 0;
    if (hipOccupancyMaxActiveBlocksPerMultiprocessor(&maxBlk, mega_k, NTHR, 0)
        != hipSuccess) maxBlk = 0;

    if (coop && maxBlk >= 1) {
        int grid = maxBlk * 256;                // 256 CUs on MI355X
        if (grid > 512) grid = 512;
        void* params[] = {
            (void*)&x, (void*)&W_in, (void*)&conv_w, (void*)&conv_b, (void*)&W_x,
            (void*)&W_dt, (void*)&b_dt, (void*)&A_log, (void*)&Dp, (void*)&W_out,
            (void*)&out, (void*)&xzT, (void*)&ixT, (void*)&ixM, (void*)&dBC,
            (void*)&gM
        };
        (void)hipLaunchCooperativeKernel((void*)mega_k, dim3(grid), dim3(NTHR),
                                         params, 0, stream);
    } else {
        k1<<<dim3(288), NTHR, 0, stream>>>(W_in, x, xzT);
        k2<<<dim3(512), NTHR, 0, stream>>>(xzT, conv_w, conv_b, ixT, ixM);
        k3<<<dim3(54),  NTHR, 0, stream>>>(ixM, W_x, dBC);
        k4<<<dim3(512), NTHR, 0, stream>>>(dBC, xzT, ixT, W_dt, b_dt, A_log, Dp, gM);
        k5<<<dim3(72),  NTHR, 0, stream>>>(gM, W_out, out);
    }
}

// Round 7
// 141.310 us; speedup vs baseline: 2.7883x; 2.7883x over previous
//
#include <hip/hip_runtime.h>

#define B_SZ 8
#define L_SEQ 144
#define NTOK 1152
#define D_MODEL 256
#define D_INNER 512
#define D_STATE 64
#define DT_RANK 4
#define LP 40
#define NTHR 256

typedef __attribute__((ext_vector_type(8))) short bf16x8;   // MFMA A/B frag
typedef __attribute__((ext_vector_type(4))) float f32x4;    // MFMA C/D frag
typedef __attribute__((ext_vector_type(4))) short short4v;

__device__ __forceinline__ unsigned short bf16_rn(float f) {
    unsigned u = __float_as_uint(f);
    u += 0x7FFF + ((u >> 16) & 1);
    return (unsigned short)(u >> 16);
}
__device__ __forceinline__ float bf16_f(unsigned short h) {
    return __uint_as_float(((unsigned)h) << 16);
}
__device__ __forceinline__ unsigned packsplit(float f) {   // hi | lo<<16
    const unsigned short h = bf16_rn(f);
    const unsigned short l = bf16_rn(f - bf16_f(h));
    return (unsigned)h | ((unsigned)l << 16);
}
__device__ __forceinline__ float unpacksum(unsigned p) {   // ~f32 reconstruct
    return bf16_f((unsigned short)(p & 0xFFFF)) + bf16_f((unsigned short)(p >> 16));
}

// ---------------------------------------------------------------------------
// One 64x64 tile of C[M,N] = A[M,K] . B[N,K]^T via bf16x3 split MFMA.
// (R4/R6-verified) APACK: A rows are packsplit u32; else f32, split in staging.
// ---------------------------------------------------------------------------
template<bool APACK, bool GN>
__device__ __forceinline__ void gemm_tile(const void* __restrict__ Aptr,
                                          const float* __restrict__ Bptr,
                                          float* __restrict__ C,
                                          const int N, const int K,
                                          const int lda, const int ldb, const int ldc,
                                          const int m0, const int n0,
                                          short* __restrict__ Ah, short* __restrict__ Al,
                                          short* __restrict__ Bh, short* __restrict__ Bl) {
    const float* Af = (const float*)Aptr;
    const unsigned* Au = (const unsigned*)Aptr;
    const int tid = threadIdx.x;
    const int w = tid >> 6, l = tid & 63;
    const int lm = l & 15, lq = l >> 4;
    const int m0w = (w >> 1) * 32, n0w = (w & 1) * 32;
    f32x4 acc[2][2] = {};

    for (int k0 = 0; k0 < K; k0 += 32) {
        unsigned short ha[2][4], la[2][4], hb[2][4], lb[2][4];
#pragma unroll
        for (int p = 0; p < 2; ++p) {
            const int i = tid + 256 * p;
            const int r = i >> 3, c = (i & 7) * 4;
            if (APACK) {
                const uint4 v = *(const uint4*)(Au + (size_t)(m0 + r) * lda + k0 + c);
                ha[p][0] = v.x & 0xFFFF; la[p][0] = v.x >> 16;
                ha[p][1] = v.y & 0xFFFF; la[p][1] = v.y >> 16;
                ha[p][2] = v.z & 0xFFFF; la[p][2] = v.z >> 16;
                ha[p][3] = v.w & 0xFFFF; la[p][3] = v.w >> 16;
            } else {
                const float4 v = *(const float4*)(Af + (size_t)(m0 + r) * lda + k0 + c);
                ha[p][0] = bf16_rn(v.x); la[p][0] = bf16_rn(v.x - bf16_f(ha[p][0]));
                ha[p][1] = bf16_rn(v.y); la[p][1] = bf16_rn(v.y - bf16_f(ha[p][1]));
                ha[p][2] = bf16_rn(v.z); la[p][2] = bf16_rn(v.z - bf16_f(ha[p][2]));
                ha[p][3] = bf16_rn(v.w); la[p][3] = bf16_rn(v.w - bf16_f(ha[p][3]));
            }
            float4 bv = make_float4(0.f, 0.f, 0.f, 0.f);
            if (!GN || (n0 + r) < N)
                bv = *(const float4*)(Bptr + (size_t)(n0 + r) * ldb + k0 + c);
            hb[p][0] = bf16_rn(bv.x); lb[p][0] = bf16_rn(bv.x - bf16_f(hb[p][0]));
            hb[p][1] = bf16_rn(bv.y); lb[p][1] = bf16_rn(bv.y - bf16_f(hb[p][1]));
            hb[p][2] = bf16_rn(bv.z); lb[p][2] = bf16_rn(bv.z - bf16_f(hb[p][2]));
            hb[p][3] = bf16_rn(bv.w); lb[p][3] = bf16_rn(bv.w - bf16_f(hb[p][3]));
        }
        __syncthreads();
#pragma unroll
        for (int p = 0; p < 2; ++p) {
            const int i = tid + 256 * p;
            const int r = i >> 3, c = (i & 7) * 4;
            const int o = r * LP + c;
            short4v v;
            v = (short4v){(short)ha[p][0], (short)ha[p][1], (short)ha[p][2], (short)ha[p][3]};
            *(short4v*)&Ah[o] = v;
            v = (short4v){(short)la[p][0], (short)la[p][1], (short)la[p][2], (short)la[p][3]};
            *(short4v*)&Al[o] = v;
            v = (short4v){(short)hb[p][0], (short)hb[p][1], (short)hb[p][2], (short)hb[p][3]};
            *(short4v*)&Bh[o] = v;
            v = (short4v){(short)lb[p][0], (short)lb[p][1], (short)lb[p][2], (short)lb[p][3]};
            *(short4v*)&Bl[o] = v;
        }
        __syncthreads();
        bf16x8 fah[2], fal[2], fbh[2], fbl[2];
#pragma unroll
        for (int t = 0; t < 2; ++t) {
            const int ao = (m0w + t * 16 + lm) * LP + lq * 8;
            fah[t] = *(const bf16x8*)&Ah[ao];
            fal[t] = *(const bf16x8*)&Al[ao];
            const int bo = (n0w + t * 16 + lm) * LP + lq * 8;
            fbh[t] = *(const bf16x8*)&Bh[bo];
            fbl[t] = *(const bf16x8*)&Bl[bo];
        }
#pragma unroll
        for (int mt = 0; mt < 2; ++mt)
#pragma unroll
            for (int nt = 0; nt < 2; ++nt) {
                acc[mt][nt] = __builtin_amdgcn_mfma_f32_16x16x32_bf16(
                    fal[mt], fbh[nt], acc[mt][nt], 0, 0, 0);
                acc[mt][nt] = __builtin_amdgcn_mfma_f32_16x16x32_bf16(
                    fah[mt], fbl[nt], acc[mt][nt], 0, 0, 0);
                acc[mt][nt] = __builtin_amdgcn_mfma_f32_16x16x32_bf16(
                    fah[mt], fbh[nt], acc[mt][nt], 0, 0, 0);
            }
    }
    // C/D layout: col = lane&15 (n), row = (lane>>4)*4 + reg (m)
#pragma unroll
    for (int mt = 0; mt < 2; ++mt) {
        const int gm = m0 + m0w + mt * 16 + lq * 4;
#pragma unroll
        for (int nt = 0; nt < 2; ++nt) {
            const int gn = n0 + n0w + nt * 16 + lm;
            if (!GN || gn < N) {
#pragma unroll
                for (int r = 0; r < 4; ++r)
                    C[(size_t)(gm + r) * ldc + gn] = acc[mt][nt][r];
            }
        }
    }
}

#define SMEM_DECL __shared__ __align__(16) char smem[4 * 64 * LP * 2]; \
    short* Ah = (short*)smem; short* Al = Ah + 64 * LP; \
    short* Bh = Al + 64 * LP; short* Bl = Bh + 64 * LP;

// k1: xzT[e][tok] = W_in . x^T   (M=1024, N=1152, K=256; 288 tiles)
__global__ __launch_bounds__(NTHR, 2) void k1(const float* __restrict__ W_in,
                                              const float* __restrict__ x,
                                              float* __restrict__ xzT) {
    SMEM_DECL;
    const int t = blockIdx.x;
    const int bx = t % 18, by = t / 18;
    gemm_tile<false, false>(W_in, x, xzT, NTOK, D_MODEL, D_MODEL, D_MODEL, NTOK,
                            by * 64, bx * 64, Ah, Al, Bh, Bl);
}

// k2: fused depthwise conv(4) + SiLU + packsplit + transpose
//     xzT[d][tok] (f32, d<512) -> ixM[tok][d] (packed u32), coalesced both sides
__global__ __launch_bounds__(NTHR) void k2(const float* __restrict__ xzT,
                                           const float* __restrict__ cw,
                                           const float* __restrict__ cb,
                                           unsigned* __restrict__ ixM) {
    __shared__ unsigned T[64][65];
    const int t0 = blockIdx.x * 64, d0 = blockIdx.y * 64;
    const int a = threadIdx.x & 15, g = threadIdx.x >> 4;
#pragma unroll
    for (int p = 0; p < 4; ++p) {
        const int d = d0 + g + 16 * p;
        const int tokbase = t0 + a * 4;
        const float* row = xzT + (size_t)d * NTOK + tokbase;
        const float4 w = *(const float4*)(cw + d * 4);
        const float bias = cb[d];
        float xv[7];
        xv[0] = (tokbase >= 2) ? row[-2] : 0.f;
        xv[1] = (tokbase >= 1) ? row[-1] : 0.f;
        const float4 v = *(const float4*)row;
        xv[2] = v.x; xv[3] = v.y; xv[4] = v.z; xv[5] = v.w;
        xv[6] = (tokbase + 4 < NTOK) ? row[4] : 0.f;
#pragma unroll
        for (int j = 0; j < 4; ++j) {
            const int tok = tokbase + j;
            const int t = tok - (tok / L_SEQ) * L_SEQ;
            float s = bias;
            if (t >= 2) s = fmaf(w.x, xv[j], s);
            if (t >= 1) s = fmaf(w.y, xv[j + 1], s);
            s = fmaf(w.z, xv[j + 2], s);
            if (t < L_SEQ - 1) s = fmaf(w.w, xv[j + 3], s);
            const float r = s * __builtin_amdgcn_rcpf(1.f + __expf(-s));
            T[g + 16 * p][a * 4 + j] = packsplit(r);
        }
    }
    __syncthreads();
#pragma unroll
    for (int p = 0; p < 4; ++p) {
        const int tt = g + 16 * p;
        uint4 o;
        o.x = T[a * 4 + 0][tt];
        o.y = T[a * 4 + 1][tt];
        o.z = T[a * 4 + 2][tt];
        o.w = T[a * 4 + 3][tt];
        *(uint4*)(ixM + (size_t)(t0 + tt) * D_INNER + d0 + a * 4) = o;
    }
}

// k3: dBC[tok][e] = ix . W_x^T   (M=1152, N=132, K=512; 54 tiles)
__global__ __launch_bounds__(NTHR, 2) void k3(const unsigned* __restrict__ ixM,
                                              const float* __restrict__ W_x,
                                              float* __restrict__ dBC) {
    SMEM_DECL;
    const int t = blockIdx.x;
    const int bx = t % 3, by = t / 3;
    gemm_tile<true, true>(ixM, W_x, dBC, 132, D_INNER, D_INNER, D_INNER, 132,
                          by * 64, bx * 64, Ah, Al, Bh, Bl);
}

// k4: fused aux + selective scan -> gM[tok][d] packed. One wave per (b,d).
// (R2-verified 32-token-chunk shape; ix from packed ixM, z from xzT)
template<int CNT>
__device__ __forceinline__ void scan_chunk(const float* __restrict__ dBC,
                                           const float* __restrict__ xzT,
                                           const unsigned* __restrict__ ixM,
                                           unsigned* __restrict__ gM,
                                           float4* __restrict__ aux_w,
                                           float (*__restrict__ Pw)[65],
                                           const int d, const int base, const int t0,
                                           const float An2, const float4 wdt,
                                           const float bdt, const float dpv,
                                           const int lane, float& h) {
    if (lane < CNT) {
        const int tok = base + t0 + lane;
        const float4 dt4 = *(const float4*)(dBC + (size_t)tok * 132);
        float s = fmaf(dt4.x, wdt.x, bdt);
        s = fmaf(dt4.y, wdt.y, s);
        s = fmaf(dt4.z, wdt.z, s);
        s = fmaf(dt4.w, wdt.w, s);
        const float delta = fmaxf(s, 0.f) + __logf(1.f + __expf(-fabsf(s)));
        const float ixv = unpacksum(ixM[(size_t)tok * D_INNER + d]);
        const float zv  = xzT[(size_t)(D_INNER + d) * NTOK + tok];
        const float sz  = zv * __builtin_amdgcn_rcpf(1.f + __expf(-zv));
        aux_w[lane] = make_float4(delta, delta * ixv, dpv * ixv, sz);
    }
#pragma unroll 8
    for (int i = 0; i < CNT; ++i) {
        const size_t rb = (size_t)(base + t0 + i) * 132;
        const float Bv = dBC[rb + DT_RANK + lane];
        const float Cv = dBC[rb + DT_RANK + D_STATE + lane];
        const float4 a4 = aux_w[i];
        const float dA = __builtin_amdgcn_exp2f(a4.x * An2);
        h = fmaf(dA, h, a4.y * Bv);
        Pw[i][lane] = h * Cv;
    }
    const int tl = lane & 31, hf = lane >> 5;
    float s2 = 0.f;
    if (tl < CNT) {
#pragma unroll
        for (int j = 0; j < 32; ++j) s2 += Pw[tl][hf * 32 + j];
    }
    s2 += __shfl_xor(s2, 32, 64);
    if (hf == 0 && tl < CNT) {
        const float4 a4 = aux_w[tl];
        gM[(size_t)(base + t0 + tl) * D_INNER + d] = packsplit((s2 + a4.z) * a4.w);
    }
}

__global__ __launch_bounds__(NTHR) void k4(const float* __restrict__ dBC,
                                           const float* __restrict__ xzT,
                                           const unsigned* __restrict__ ixM,
                                           const float* __restrict__ W_dt,
                                           const float* __restrict__ b_dt,
                                           const float* __restrict__ A_log,
                                           const float* __restrict__ Dp,
                                           unsigned* __restrict__ gM) {
    __shared__ float4 aux_s[4][32];
    __shared__ float P[4][32][65];
    const int w = threadIdx.x >> 6, lane = threadIdx.x & 63;
    const int b = blockIdx.x >> 7, dg = blockIdx.x & 127;
    const int d = (dg << 2) | w;
    const int base = b * L_SEQ;
    const float An2 = -__expf(A_log[(d << 6) + lane]) * 1.44269504088896f;
    const float4 wdt = *(const float4*)(W_dt + (d << 2));
    const float bdt = b_dt[d], dpv = Dp[d];
    float4* aux_w = aux_s[w];
    float (*Pw)[65] = P[w];
    float h = 0.f;
    scan_chunk<32>(dBC, xzT, ixM, gM, aux_w, Pw, d, base, 0,   An2, wdt, bdt, dpv, lane, h);
    scan_chunk<32>(dBC, xzT, ixM, gM, aux_w, Pw, d, base, 32,  An2, wdt, bdt, dpv, lane, h);
    scan_chunk<32>(dBC, xzT, ixM, gM, aux_w, Pw, d, base, 64,  An2, wdt, bdt, dpv, lane, h);
    scan_chunk<32>(dBC, xzT, ixM, gM, aux_w, Pw, d, base, 96,  An2, wdt, bdt, dpv, lane, h);
    scan_chunk<16>(dBC, xzT, ixM, gM, aux_w, Pw, d, base, 128, An2, wdt, bdt, dpv, lane, h);
}

// k5: out[tok][e] = g . W_out^T  (M=1152, N=256, K=512; 72 tiles)
__global__ __launch_bounds__(NTHR, 2) void k5(const unsigned* __restrict__ gM,
                                              const float* __restrict__ W_out,
                                              float* __restrict__ out) {
    SMEM_DECL;
    const int t = blockIdx.x;
    const int bx = t % 4, by = t / 4;
    gemm_tile<true, false>(gM, W_out, out, D_MODEL, D_INNER, D_INNER, D_INNER,
                           D_MODEL, by * 64, bx * 64, Ah, Al, Bh, Bl);
}

// ---------------------------------------------------------------------------
extern "C" void kernel_launch(void* const* d_in, const int* in_sizes, int n_in,
                              void* d_out, int out_size, void* d_ws, size_t ws_size,
                              hipStream_t stream) {
    const float* x      = (const float*)d_in[0];
    // d_in[1] = lastin (unused: reference starts from h0 = 0)
    const float* W_in   = (const float*)d_in[2];
    const float* conv_w = (const float*)d_in[3];
    const float* conv_b = (const float*)d_in[4];
    const float* W_x    = (const float*)d_in[5];
    const float* W_dt   = (const float*)d_in[6];
    const float* b_dt   = (const float*)d_in[7];
    const float* A_log  = (const float*)d_in[8];
    const float* Dp     = (const float*)d_in[9];
    const float* W_out  = (const float*)d_in[10];
    float* out = (float*)d_out;

    float* ws  = (float*)d_ws;
    float* xzT = ws;                            // [1024][1152] f32
    float* dBC = xzT + 1179648;                 // [1152][132]  f32
    unsigned* ixM = (unsigned*)(dBC + 152064);  // [1152][512]  packed bf16 pair
    unsigned* gM  = ixM + 589824;               // [1152][512]  packed bf16 pair

    k1<<<dim3(288), NTHR, 0, stream>>>(W_in, x, xzT);
    k2<<<dim3(18, 8), NTHR, 0, stream>>>(xzT, conv_w, conv_b, ixM);
    k3<<<dim3(54), NTHR, 0, stream>>>(ixM, W_x, dBC);
    k4<<<dim3(1024), NTHR, 0, stream>>>(dBC, xzT, ixM, W_dt, b_dt, A_log, Dp, gM);
    k5<<<dim3(72), NTHR, 0, stream>>>(gM, W_out, out);
}